// Round 11
// baseline (232.704 us; speedup 1.0000x reference)
//
#include <hip/hip_runtime.h>
#include <hip/hip_bf16.h>

// ---------------------------------------------------------------------------
// GCN 2-layer forward, round 11. Best-known base = round 8 (205.6us), plus:
//  - k_fused1: XCD-partitioned scatter (blocks 0..2047, r8 body, vectorized
//    edge loads) || BK=32-chunked MFMA GEMM1 (15.3KB LDS -> scatter blocks
//    keep 8 blocks/CU; r3's 52KB-LDS fusion failure avoided). GEMM1 writes
//    hb UNSCALED (cnt not final mid-kernel) with NT stores.
//  - agg128 reverts to r5's validated pre-gathered-weight scheme (cnt is
//    200KB L2-resident; r7 showed weight gathers ~free).
//  - GEMM2 fused into agg128 epilogue: h1 row -> LDS, per-lane 128-FMA dot
//    vs block-staged bf16 W2 (17KB LDS), scaled by isd_i -> h2b. Deletes
//    gemm2 dispatch + h1b buffer + ~25MB traffic; VALU/LDS work hides in
//    the gather loop's idle slots.
//  - k_agg64 = r8 verbatim (prescaled h2 rows, fp32 out).
// Round-10 lesson: src-sorted CSR (compact) regressed -> reverted.
// Known fixed cost: harness d_ws re-poison ~45us + restores (~60us tax).
// ---------------------------------------------------------------------------

#define GCN_IN   128
#define GCN_H    128
#define GCN_OUT  64
#define CAP      64
#define OVF_CAP  65536
#define SCAT_BLOCKS 2048   // 8 partitions x 256 blocks

using short8 = __attribute__((ext_vector_type(8))) short;   // 8 bf16, 4 VGPRs
using f32x4  = __attribute__((ext_vector_type(4))) float;   // MFMA acc
using int4v  = __attribute__((ext_vector_type(4))) int;     // native vec4 int

__device__ __forceinline__ ushort f2bf(float f) {     // fp32 -> bf16 RNE
    uint b = __float_as_uint(f);
    b = (b + 0x7FFFu + ((b >> 16) & 1u)) >> 16;
    return (ushort)b;
}
__device__ __forceinline__ float bf2f_lo(uint u) { return __uint_as_float(u << 16); }
__device__ __forceinline__ float bf2f_hi(uint u) { return __uint_as_float(u & 0xFFFF0000u); }

// ---------------- fused: [0,SCAT) scatter || [SCAT,..) MFMA GEMM1 -----------
// GEMM1: hb[N][128] bf16 UNSCALED = x_f32[N][128] @ W1_f32[128][128]
__global__ __launch_bounds__(256) void k_fused1(
        const int* __restrict__ src, const int* __restrict__ dst,
        int* __restrict__ cnt, ushort* __restrict__ slot,
        int* __restrict__ ovfcnt, int2* __restrict__ ovf, int E,
        const float* __restrict__ A, const float* __restrict__ B,
        ushort* __restrict__ C, int M, int N) {
    __shared__ __align__(16) ushort As[64][40];    // [m][k-chunk] bf16
    __shared__ __align__(16) ushort Bs[128][40];   // [n][k-chunk] bf16 (W1^T)
    const int tid = threadIdx.x;

    if (blockIdx.x < SCAT_BLOCKS) {
        const int part = blockIdx.x & 7;           // round-robin -> XCD part
        const int psz  = (N + 7) >> 3;
        const int lo   = part * psz;
        const int hi   = min(lo + psz, N);
        const int bip  = blockIdx.x >> 3;          // 0..255 within partition
        const int stride4 = (SCAT_BLOCKS >> 3) * 256 * 4;
        for (int e = (bip * 256 + tid) * 4; e < E; e += stride4) {
            int4v d4 = __builtin_nontemporal_load((const int4v*)(dst + e));
            int4v s4 = __builtin_nontemporal_load((const int4v*)(src + e));
            #pragma unroll
            for (int k = 0; k < 4; ++k) {
                int d = d4[k];
                int s = s4[k];
                if (d >= lo && d < hi) {
                    int pos = atomicAdd(&cnt[d], 1);
                    if (pos < CAP) {
                        slot[(size_t)d * CAP + pos] = (ushort)s;  // L2 window
                    } else {
                        int q = atomicAdd(ovfcnt, 1);
                        if (q < OVF_CAP) ovf[q] = make_int2(d, s);
                    }
                }
            }
        }
        return;
    }

    // ---- MFMA GEMM1: 64 rows x 128 cols per block, BK=32 chunks ----
    const int g    = blockIdx.x - SCAT_BLOCKS;
    const int row0 = g * 64;
    const int w    = tid >> 6;
    const int lane = tid & 63;
    const int l15  = lane & 15;
    const int q8   = (lane >> 4) * 8;

    f32x4 acc[8];
    #pragma unroll
    for (int t = 0; t < 8; ++t) {
        acc[t][0] = 0.f; acc[t][1] = 0.f; acc[t][2] = 0.f; acc[t][3] = 0.f;
    }
    for (int kb = 0; kb < 128; kb += 32) {
        // stage A chunk: 64 rows x 32 k, fp32 -> bf16, vector LDS writes
        #pragma unroll
        for (int tt = 0; tt < 2; ++tt) {
            int f = tid * 4 + tt * 1024;
            int r = f >> 5;
            int k = f & 31;
            float4 v = make_float4(0.f, 0.f, 0.f, 0.f);
            int gr = row0 + r;
            if (gr < M) v = *(const float4*)(A + (size_t)gr * 128 + kb + k);
            ushort4 o;
            o.x = f2bf(v.x); o.y = f2bf(v.y); o.z = f2bf(v.z); o.w = f2bf(v.w);
            *(ushort4*)&As[r][k] = o;
        }
        // stage B chunk: W1[kb+k][n] -> Bs[n][k] (transpose)
        #pragma unroll
        for (int tt = 0; tt < 4; ++tt) {
            int f = tid * 4 + tt * 1024;
            int k = f >> 7;
            int n = f & 127;
            float4 v = *(const float4*)(B + (size_t)(kb + k) * 128 + n);
            Bs[n + 0][k] = f2bf(v.x);
            Bs[n + 1][k] = f2bf(v.y);
            Bs[n + 2][k] = f2bf(v.z);
            Bs[n + 3][k] = f2bf(v.w);
        }
        __syncthreads();
        short8 a = *(const short8*)&As[16 * w + l15][q8];
        #pragma unroll
        for (int t = 0; t < 8; ++t) {
            short8 b = *(const short8*)&Bs[16 * t + l15][q8];
            acc[t] = __builtin_amdgcn_mfma_f32_16x16x32_bf16(a, b, acc[t], 0, 0, 0);
        }
        __syncthreads();
    }
    const int quad = lane >> 4;
    #pragma unroll
    for (int r = 0; r < 4; ++r) {
        int grow = row0 + 16 * w + quad * 4 + r;
        if (grow < M) {
            #pragma unroll
            for (int t = 0; t < 8; ++t) {
                __builtin_nontemporal_store(
                    f2bf(acc[t][r]), C + (size_t)grow * 128 + 16 * t + l15);
            }
        }
    }
}

// ---------------- fused agg layer 1 + GEMM2 ---------------------------------
// Wave per node (4/block). Phase A (r5-validated): pre-gathered weights,
// quad-wide uint4 gathers, fold, relu(isd_i*(sum + isd_i*self)+b1) -> h1s
// (LDS, bf16). Phase B: lane n computes h2[node][n] = isd_i * <h1, W2[:,n]>
// via 16x b128 LDS reads (h1 broadcast + W2s), writes bf16 h2b.
__global__ __launch_bounds__(256) void k_agg128g2(
        const ushort* __restrict__ h,        // hb, N x 128 bf16 (unscaled)
        const int* __restrict__ cnt,
        const ushort* __restrict__ slot,
        const float* __restrict__ bias,      // b1
        const int* __restrict__ ovfcnt,
        const int2* __restrict__ ovf,
        const float* __restrict__ W2,        // 128 x 64 f32
        ushort* __restrict__ h2b,            // N x 64 bf16 (isd-scaled)
        int n) {
    __shared__ __align__(16) ushort W2s[64][136];  // [n][k] bf16
    __shared__ __align__(16) ushort h1s[4][136];   // [wave][k] bf16
    const int tid  = threadIdx.x;
    const int w    = tid >> 6;
    const int lane = tid & 63;
    const int node = blockIdx.x * 4 + w;

    // stage W2 (once per block): W2[k][nn] -> W2s[nn][k] bf16
    #pragma unroll
    for (int tt = 0; tt < 8; ++tt) {
        int f = tid * 4 + tt * 1024;
        int k = f >> 6;
        int nn = f & 63;
        float4 v = *(const float4*)(W2 + (size_t)k * 64 + nn);
        W2s[nn + 0][k] = f2bf(v.x);
        W2s[nn + 1][k] = f2bf(v.y);
        W2s[nn + 2][k] = f2bf(v.z);
        W2s[nn + 3][k] = f2bf(v.w);
    }

    float isd_i = 0.f;
    if (node < n) {
        int deg = cnt[node];
        int degm = min(deg, CAP);
        isd_i = rsqrtf((float)(deg + 1));
        int sidx = (int)__builtin_nontemporal_load(slot + (size_t)node * CAP + lane);
        bool valid = lane < degm;
        if (!valid) sidx = 0;
        float wl = valid ? rsqrtf((float)(cnt[sidx] + 1)) : 0.f;

        const int q = lane >> 4;          // 0..3
        const int i = lane & 15;          // 0..15
        const ushort* hp = h + 8 * i;     // 8 bf16 feats per lane

        float acc[8] = {};
        for (int j = 0; j < degm; j += 8) {       // 8 edges/iter, 2 gathers
            int j0 = j + q;
            int j1 = j + 4 + q;
            int   s0 = __shfl(sidx, j0);
            int   s1 = __shfl(sidx, j1);
            float w0 = __shfl(wl, j0);            // 0 beyond degm
            float w1 = __shfl(wl, j1);
            uint4 v0 = *(const uint4*)(hp + (size_t)s0 * 128);
            uint4 v1 = *(const uint4*)(hp + (size_t)s1 * 128);
            acc[0] += w0 * bf2f_lo(v0.x) + w1 * bf2f_lo(v1.x);
            acc[1] += w0 * bf2f_hi(v0.x) + w1 * bf2f_hi(v1.x);
            acc[2] += w0 * bf2f_lo(v0.y) + w1 * bf2f_lo(v1.y);
            acc[3] += w0 * bf2f_hi(v0.y) + w1 * bf2f_hi(v1.y);
            acc[4] += w0 * bf2f_lo(v0.z) + w1 * bf2f_lo(v1.z);
            acc[5] += w0 * bf2f_hi(v0.z) + w1 * bf2f_hi(v1.z);
            acc[6] += w0 * bf2f_lo(v0.w) + w1 * bf2f_lo(v1.w);
            acc[7] += w0 * bf2f_hi(v0.w) + w1 * bf2f_hi(v1.w);
        }
        int ovn = *ovfcnt;                         // ~always 0
        for (int t = 0; t < ovn; ++t) {
            int2 p = ovf[t];
            if (p.x == node && q == 0) {
                float w0 = rsqrtf((float)(cnt[p.y] + 1));
                uint4 v0 = *(const uint4*)(hp + (size_t)p.y * 128);
                acc[0] += w0 * bf2f_lo(v0.x); acc[1] += w0 * bf2f_hi(v0.x);
                acc[2] += w0 * bf2f_lo(v0.y); acc[3] += w0 * bf2f_hi(v0.y);
                acc[4] += w0 * bf2f_lo(v0.z); acc[5] += w0 * bf2f_hi(v0.z);
                acc[6] += w0 * bf2f_lo(v0.w); acc[7] += w0 * bf2f_hi(v0.w);
            }
        }
        #pragma unroll
        for (int k = 0; k < 8; ++k) {              // fold quads
            acc[k] += __shfl_xor(acc[k], 16);
            acc[k] += __shfl_xor(acc[k], 32);
        }
        if (q == 0) {
            uint4 vs = *(const uint4*)(hp + (size_t)node * 128);  // self
            float4 ba = *(const float4*)(bias + 8 * i);
            float4 bb = *(const float4*)(bias + 8 * i + 4);
            float r0 = fmaxf((acc[0] + isd_i * bf2f_lo(vs.x)) * isd_i + ba.x, 0.f);
            float r1 = fmaxf((acc[1] + isd_i * bf2f_hi(vs.x)) * isd_i + ba.y, 0.f);
            float r2 = fmaxf((acc[2] + isd_i * bf2f_lo(vs.y)) * isd_i + ba.z, 0.f);
            float r3 = fmaxf((acc[3] + isd_i * bf2f_hi(vs.y)) * isd_i + ba.w, 0.f);
            float r4 = fmaxf((acc[4] + isd_i * bf2f_lo(vs.z)) * isd_i + bb.x, 0.f);
            float r5 = fmaxf((acc[5] + isd_i * bf2f_hi(vs.z)) * isd_i + bb.y, 0.f);
            float r6 = fmaxf((acc[6] + isd_i * bf2f_lo(vs.w)) * isd_i + bb.z, 0.f);
            float r7 = fmaxf((acc[7] + isd_i * bf2f_hi(vs.w)) * isd_i + bb.w, 0.f);
            uint4 o;
            o.x = (uint)f2bf(r0) | ((uint)f2bf(r1) << 16);
            o.y = (uint)f2bf(r2) | ((uint)f2bf(r3) << 16);
            o.z = (uint)f2bf(r4) | ((uint)f2bf(r5) << 16);
            o.w = (uint)f2bf(r6) | ((uint)f2bf(r7) << 16);
            *(uint4*)&h1s[w][8 * i] = o;
        }
    }
    __syncthreads();   // h1s + W2s visible to all

    // ---- phase B: h2[node][lane] = isd_i * <h1s[w], W2s[lane]> ----
    if (node < n) {
        float s = 0.f;
        #pragma unroll
        for (int kk = 0; kk < 16; ++kk) {
            uint4 hv = *(const uint4*)&h1s[w][8 * kk];      // broadcast
            uint4 wv = *(const uint4*)&W2s[lane][8 * kk];
            s += bf2f_lo(hv.x) * bf2f_lo(wv.x) + bf2f_hi(hv.x) * bf2f_hi(wv.x);
            s += bf2f_lo(hv.y) * bf2f_lo(wv.y) + bf2f_hi(hv.y) * bf2f_hi(wv.y);
            s += bf2f_lo(hv.z) * bf2f_lo(wv.z) + bf2f_hi(hv.z) * bf2f_hi(wv.z);
            s += bf2f_lo(hv.w) * bf2f_lo(wv.w) + bf2f_hi(hv.w) * bf2f_hi(wv.w);
        }
        __builtin_nontemporal_store(f2bf(isd_i * s),
                                    h2b + (size_t)node * 64 + lane);
    }
}

// ---------------- agg layer 2: F=64, prescaled bf16 in, fp32 out ------------
__global__ __launch_bounds__(256) void k_agg64(const ushort* __restrict__ h,
                                               const int* __restrict__ cnt,
                                               const ushort* __restrict__ slot,
                                               const float* __restrict__ bias,
                                               const int* __restrict__ ovfcnt,
                                               const int2* __restrict__ ovf,
                                               float* __restrict__ out, int n) {
    int node = (blockIdx.x * 256 + threadIdx.x) >> 6;
    int lane = threadIdx.x & 63;
    if (node >= n) return;
    int deg = cnt[node];
    int degm = min(deg, CAP);
    float isd_i = rsqrtf((float)(deg + 1));
    int sidx = (int)__builtin_nontemporal_load(slot + (size_t)node * CAP + lane);

    const int g = lane >> 3;          // 0..7
    const int i = lane & 7;           // 0..7
    const ushort* hp = h + 8 * i;

    float acc[8] = {};
    for (int j = 0; j < degm; j += 16) {         // 16 edges/iter, 2 gathers
        int j0 = j + g;
        int j1 = j + 8 + g;
        int   s0 = __shfl(sidx, j0);
        int   s1 = __shfl(sidx, j1);
        float w0 = (j0 < degm) ? 1.f : 0.f;
        float w1 = (j1 < degm) ? 1.f : 0.f;
        uint4 v0 = *(const uint4*)(hp + (size_t)s0 * 64);
        uint4 v1 = *(const uint4*)(hp + (size_t)s1 * 64);
        acc[0] += w0 * bf2f_lo(v0.x) + w1 * bf2f_lo(v1.x);
        acc[1] += w0 * bf2f_hi(v0.x) + w1 * bf2f_hi(v1.x);
        acc[2] += w0 * bf2f_lo(v0.y) + w1 * bf2f_lo(v1.y);
        acc[3] += w0 * bf2f_hi(v0.y) + w1 * bf2f_hi(v1.y);
        acc[4] += w0 * bf2f_lo(v0.z) + w1 * bf2f_lo(v1.z);
        acc[5] += w0 * bf2f_hi(v0.z) + w1 * bf2f_hi(v1.z);
        acc[6] += w0 * bf2f_lo(v0.w) + w1 * bf2f_lo(v1.w);
        acc[7] += w0 * bf2f_hi(v0.w) + w1 * bf2f_hi(v1.w);
    }
    int ovn = *ovfcnt;
    for (int t = 0; t < ovn; ++t) {
        int2 p = ovf[t];
        if (p.x == node && g == 0) {             // h2 rows prescaled by isd_s
            uint4 v0 = *(const uint4*)(hp + (size_t)p.y * 64);
            acc[0] += bf2f_lo(v0.x); acc[1] += bf2f_hi(v0.x);
            acc[2] += bf2f_lo(v0.y); acc[3] += bf2f_hi(v0.y);
            acc[4] += bf2f_lo(v0.z); acc[5] += bf2f_hi(v0.z);
            acc[6] += bf2f_lo(v0.w); acc[7] += bf2f_hi(v0.w);
        }
    }
    #pragma unroll
    for (int k = 0; k < 8; ++k) {                // fold octs
        acc[k] += __shfl_xor(acc[k], 8);
        acc[k] += __shfl_xor(acc[k], 16);
        acc[k] += __shfl_xor(acc[k], 32);
    }
    if (g == 0) {
        uint4 vs = *(const uint4*)(hp + (size_t)node * 64);   // scaled self
        float4 ba = *(const float4*)(bias + 8 * i);
        float4 bb = *(const float4*)(bias + 8 * i + 4);
        float4 r0, r1;
        r0.x = (acc[0] + bf2f_lo(vs.x)) * isd_i + ba.x;
        r0.y = (acc[1] + bf2f_hi(vs.x)) * isd_i + ba.y;
        r0.z = (acc[2] + bf2f_lo(vs.y)) * isd_i + ba.z;
        r0.w = (acc[3] + bf2f_hi(vs.y)) * isd_i + ba.w;
        r1.x = (acc[4] + bf2f_lo(vs.z)) * isd_i + bb.x;
        r1.y = (acc[5] + bf2f_hi(vs.z)) * isd_i + bb.y;
        r1.z = (acc[6] + bf2f_lo(vs.w)) * isd_i + bb.z;
        r1.w = (acc[7] + bf2f_hi(vs.w)) * isd_i + bb.w;
        float* op = out + (size_t)node * 64 + 8 * i;
        *(float4*)op = r0;
        *(float4*)(op + 4) = r1;
    }
}

static inline size_t align256(size_t x) { return (x + 255) & ~(size_t)255; }

extern "C" void kernel_launch(void* const* d_in, const int* in_sizes, int n_in,
                              void* d_out, int out_size, void* d_ws, size_t ws_size,
                              hipStream_t stream) {
    const float* x  = (const float*)d_in[0];
    const int*   ei = (const int*)d_in[1];
    const float* W1 = (const float*)d_in[2];
    const float* b1 = (const float*)d_in[3];
    const float* W2 = (const float*)d_in[4];
    const float* b2 = (const float*)d_in[5];
    float* out = (float*)d_out;

    const int N = in_sizes[0] / GCN_IN;   // 50000
    const int E = in_sizes[1] / 2;        // 800000
    const int* src = ei;
    const int* dst = ei + E;

    char* ws = (char*)d_ws;
    size_t o = 0;
    int*    cnt    = (int*)(ws + o);     o += align256((size_t)N * 4);
    int*    ovfcnt = (int*)(ws + o);     o += 256;
    int2*   ovf    = (int2*)(ws + o);    o += align256((size_t)OVF_CAP * 8);
    ushort* slot   = (ushort*)(ws + o);  o += align256((size_t)N * CAP * 2);
    ushort* hb     = (ushort*)(ws + o);  o += align256((size_t)N * GCN_H * 2);
    ushort* h2b    = (ushort*)(ws + o);  o += align256((size_t)N * GCN_OUT * 2);

    // zero cnt + ovfcnt (contiguous)
    (void)hipMemsetAsync(cnt, 0, align256((size_t)N * 4) + 256, stream);

    // 1. fused: XCD-partitioned scatter || MFMA GEMM1 -> hb (unscaled bf16)
    {
        int gemm_blocks = (N + 63) / 64;
        k_fused1<<<SCAT_BLOCKS + gemm_blocks, 256, 0, stream>>>(
            src, dst, cnt, slot, ovfcnt, ovf, E, x, W1, hb, N, N);
    }

    // 2. fused agg layer 1 + GEMM2 -> h2b (bf16, isd-scaled)
    k_agg128g2<<<(N + 3) / 4, 256, 0, stream>>>(hb, cnt, slot, b1,
                                                ovfcnt, ovf, W2, h2b, N);

    // 3. agg layer 2 -> out (fp32)
    k_agg64<<<(N * 64 + 255) / 256, 256, 0, stream>>>(h2b, cnt, slot, b2,
                                                      ovfcnt, ovf, out, N);
}

// Round 12
// 200.629 us; speedup vs baseline: 1.1599x; 1.1599x over previous
//
#include <hip/hip_runtime.h>
#include <hip/hip_bf16.h>

// ---------------------------------------------------------------------------
// GCN 2-layer forward, round 12.
// = round 8 chain with the ONE validated r11 win kept:
//  - k_fused1: XCD-partitioned scatter (blocks 0..2047) || BK=32 MFMA GEMM1
//    (15.3KB LDS). GEMM1's ~8us hides under the ~62us scatter for free
//    (r11 budget: fused1 ~= scatter alone). hb written UNSCALED (NT stores).
//  - k_agg128: r8 wave-per-node wide-gather shape + r5/r7 per-edge weight
//    gather (cnt is 200KB L2-resident; r7 showed weight gathers ~free).
//  - k_gemm2 / k_agg64: r8 verbatim (gemm2 isd-scales h2 rows; agg64
//    consumes prescaled rows).
// r11 lesson: fusing GEMM2 into agg128 epilogue = VALU+LDS-conflict bound
// (80% VALUBusy, 2.2e7 bank conflicts) -> reverted.
// r10 lesson: src-sorted CSR doesn't improve gather service -> not used.
// Fixed cost: harness d_ws re-poison + restores ~55us inside timed window.
// ---------------------------------------------------------------------------

#define GCN_IN   128
#define GCN_H    128
#define GCN_OUT  64
#define CAP      64
#define OVF_CAP  65536
#define SCAT_BLOCKS 2048   // 8 partitions x 256 blocks

using short8 = __attribute__((ext_vector_type(8))) short;   // 8 bf16, 4 VGPRs
using f32x4  = __attribute__((ext_vector_type(4))) float;   // MFMA acc
using int4v  = __attribute__((ext_vector_type(4))) int;     // native vec4 int

__device__ __forceinline__ ushort f2bf(float f) {     // fp32 -> bf16 RNE
    uint b = __float_as_uint(f);
    b = (b + 0x7FFFu + ((b >> 16) & 1u)) >> 16;
    return (ushort)b;
}
__device__ __forceinline__ float bf2f_lo(uint u) { return __uint_as_float(u << 16); }
__device__ __forceinline__ float bf2f_hi(uint u) { return __uint_as_float(u & 0xFFFF0000u); }

// ---------------- fused: [0,SCAT) scatter || [SCAT,..) MFMA GEMM1 -----------
// GEMM1: hb[N][128] bf16 UNSCALED = x_f32[N][128] @ W1_f32[128][128]
__global__ __launch_bounds__(256) void k_fused1(
        const int* __restrict__ src, const int* __restrict__ dst,
        int* __restrict__ cnt, ushort* __restrict__ slot,
        int* __restrict__ ovfcnt, int2* __restrict__ ovf, int E,
        const float* __restrict__ A, const float* __restrict__ B,
        ushort* __restrict__ C, int M, int N) {
    __shared__ __align__(16) ushort As[64][40];    // [m][k-chunk] bf16
    __shared__ __align__(16) ushort Bs[128][40];   // [n][k-chunk] bf16 (W1^T)
    const int tid = threadIdx.x;

    if (blockIdx.x < SCAT_BLOCKS) {
        const int part = blockIdx.x & 7;           // round-robin -> XCD part
        const int psz  = (N + 7) >> 3;
        const int lo   = part * psz;
        const int hi   = min(lo + psz, N);
        const int bip  = blockIdx.x >> 3;          // 0..255 within partition
        const int stride4 = (SCAT_BLOCKS >> 3) * 256 * 4;
        for (int e = (bip * 256 + tid) * 4; e < E; e += stride4) {
            int4v d4 = __builtin_nontemporal_load((const int4v*)(dst + e));
            int4v s4 = __builtin_nontemporal_load((const int4v*)(src + e));
            #pragma unroll
            for (int k = 0; k < 4; ++k) {
                int d = d4[k];
                int s = s4[k];
                if (d >= lo && d < hi) {
                    int pos = atomicAdd(&cnt[d], 1);
                    if (pos < CAP) {
                        slot[(size_t)d * CAP + pos] = (ushort)s;  // L2 window
                    } else {
                        int q = atomicAdd(ovfcnt, 1);
                        if (q < OVF_CAP) ovf[q] = make_int2(d, s);
                    }
                }
            }
        }
        return;
    }

    // ---- MFMA GEMM1: 64 rows x 128 cols per block, BK=32 chunks ----
    const int g    = blockIdx.x - SCAT_BLOCKS;
    const int row0 = g * 64;
    const int w    = tid >> 6;
    const int lane = tid & 63;
    const int l15  = lane & 15;
    const int q8   = (lane >> 4) * 8;

    f32x4 acc[8];
    #pragma unroll
    for (int t = 0; t < 8; ++t) {
        acc[t][0] = 0.f; acc[t][1] = 0.f; acc[t][2] = 0.f; acc[t][3] = 0.f;
    }
    for (int kb = 0; kb < 128; kb += 32) {
        #pragma unroll
        for (int tt = 0; tt < 2; ++tt) {
            int f = tid * 4 + tt * 1024;
            int r = f >> 5;
            int k = f & 31;
            float4 v = make_float4(0.f, 0.f, 0.f, 0.f);
            int gr = row0 + r;
            if (gr < M) v = *(const float4*)(A + (size_t)gr * 128 + kb + k);
            ushort4 o;
            o.x = f2bf(v.x); o.y = f2bf(v.y); o.z = f2bf(v.z); o.w = f2bf(v.w);
            *(ushort4*)&As[r][k] = o;
        }
        #pragma unroll
        for (int tt = 0; tt < 4; ++tt) {
            int f = tid * 4 + tt * 1024;
            int k = f >> 7;
            int n = f & 127;
            float4 v = *(const float4*)(B + (size_t)(kb + k) * 128 + n);
            Bs[n + 0][k] = f2bf(v.x);
            Bs[n + 1][k] = f2bf(v.y);
            Bs[n + 2][k] = f2bf(v.z);
            Bs[n + 3][k] = f2bf(v.w);
        }
        __syncthreads();
        short8 a = *(const short8*)&As[16 * w + l15][q8];
        #pragma unroll
        for (int t = 0; t < 8; ++t) {
            short8 b = *(const short8*)&Bs[16 * t + l15][q8];
            acc[t] = __builtin_amdgcn_mfma_f32_16x16x32_bf16(a, b, acc[t], 0, 0, 0);
        }
        __syncthreads();
    }
    const int quad = lane >> 4;
    #pragma unroll
    for (int r = 0; r < 4; ++r) {
        int grow = row0 + 16 * w + quad * 4 + r;
        if (grow < M) {
            #pragma unroll
            for (int t = 0; t < 8; ++t) {
                __builtin_nontemporal_store(
                    f2bf(acc[t][r]), C + (size_t)grow * 128 + 16 * t + l15);
            }
        }
    }
}

// ---------------- agg layer 1: F=128, unscaled bf16 in, bf16 out, relu ------
// Wave per node. Per-edge weight = isd[src] gathered from L2-resident cnt.
// Quad q: edges j+q / j+4+q; lane holds feats 8i..8i+7 via one uint4 = 4 rows.
__global__ __launch_bounds__(256) void k_agg128(const ushort* __restrict__ h,
                                                const int* __restrict__ cnt,
                                                const ushort* __restrict__ slot,
                                                const float* __restrict__ bias,
                                                const int* __restrict__ ovfcnt,
                                                const int2* __restrict__ ovf,
                                                ushort* __restrict__ out, int n) {
    int node = (blockIdx.x * 256 + threadIdx.x) >> 6;
    int lane = threadIdx.x & 63;
    if (node >= n) return;
    int deg = cnt[node];
    int degm = min(deg, CAP);
    float isd_i = rsqrtf((float)(deg + 1));
    int sidx = (int)__builtin_nontemporal_load(slot + (size_t)node * CAP + lane);
    bool valid = lane < degm;
    if (!valid) sidx = 0;
    float wl = valid ? rsqrtf((float)(cnt[sidx] + 1)) : 0.f;

    const int q = lane >> 4;          // 0..3
    const int i = lane & 15;          // 0..15
    const ushort* hp = h + 8 * i;     // 8 bf16 feats per lane

    float acc[8] = {};
    for (int j = 0; j < degm; j += 8) {          // 8 edges/iter, 2 gathers
        int j0 = j + q;
        int j1 = j + 4 + q;
        int   s0 = __shfl(sidx, j0);
        int   s1 = __shfl(sidx, j1);
        float w0 = __shfl(wl, j0);               // 0 beyond degm
        float w1 = __shfl(wl, j1);
        uint4 v0 = *(const uint4*)(hp + (size_t)s0 * 128);
        uint4 v1 = *(const uint4*)(hp + (size_t)s1 * 128);
        acc[0] += w0 * bf2f_lo(v0.x) + w1 * bf2f_lo(v1.x);
        acc[1] += w0 * bf2f_hi(v0.x) + w1 * bf2f_hi(v1.x);
        acc[2] += w0 * bf2f_lo(v0.y) + w1 * bf2f_lo(v1.y);
        acc[3] += w0 * bf2f_hi(v0.y) + w1 * bf2f_hi(v1.y);
        acc[4] += w0 * bf2f_lo(v0.z) + w1 * bf2f_lo(v1.z);
        acc[5] += w0 * bf2f_hi(v0.z) + w1 * bf2f_hi(v1.z);
        acc[6] += w0 * bf2f_lo(v0.w) + w1 * bf2f_lo(v1.w);
        acc[7] += w0 * bf2f_hi(v0.w) + w1 * bf2f_hi(v1.w);
    }
    int ovn = *ovfcnt;                            // ~always 0
    for (int t = 0; t < ovn; ++t) {
        int2 p = ovf[t];
        if (p.x == node && q == 0) {
            float w0 = rsqrtf((float)(cnt[p.y] + 1));
            uint4 v0 = *(const uint4*)(hp + (size_t)p.y * 128);
            acc[0] += w0 * bf2f_lo(v0.x); acc[1] += w0 * bf2f_hi(v0.x);
            acc[2] += w0 * bf2f_lo(v0.y); acc[3] += w0 * bf2f_hi(v0.y);
            acc[4] += w0 * bf2f_lo(v0.z); acc[5] += w0 * bf2f_hi(v0.z);
            acc[6] += w0 * bf2f_lo(v0.w); acc[7] += w0 * bf2f_hi(v0.w);
        }
    }
    #pragma unroll
    for (int k = 0; k < 8; ++k) {                 // fold quads
        acc[k] += __shfl_xor(acc[k], 16);
        acc[k] += __shfl_xor(acc[k], 32);
    }
    if (q == 0) {
        uint4 vs = *(const uint4*)(hp + (size_t)node * 128);  // self (unscaled)
        float4 ba = *(const float4*)(bias + 8 * i);
        float4 bb = *(const float4*)(bias + 8 * i + 4);
        float r0 = fmaxf((acc[0] + isd_i * bf2f_lo(vs.x)) * isd_i + ba.x, 0.f);
        float r1 = fmaxf((acc[1] + isd_i * bf2f_hi(vs.x)) * isd_i + ba.y, 0.f);
        float r2 = fmaxf((acc[2] + isd_i * bf2f_lo(vs.y)) * isd_i + ba.z, 0.f);
        float r3 = fmaxf((acc[3] + isd_i * bf2f_hi(vs.y)) * isd_i + ba.w, 0.f);
        float r4 = fmaxf((acc[4] + isd_i * bf2f_lo(vs.z)) * isd_i + bb.x, 0.f);
        float r5 = fmaxf((acc[5] + isd_i * bf2f_hi(vs.z)) * isd_i + bb.y, 0.f);
        float r6 = fmaxf((acc[6] + isd_i * bf2f_lo(vs.w)) * isd_i + bb.z, 0.f);
        float r7 = fmaxf((acc[7] + isd_i * bf2f_hi(vs.w)) * isd_i + bb.w, 0.f);
        uint4 o;
        o.x = (uint)f2bf(r0) | ((uint)f2bf(r1) << 16);
        o.y = (uint)f2bf(r2) | ((uint)f2bf(r3) << 16);
        o.z = (uint)f2bf(r4) | ((uint)f2bf(r5) << 16);
        o.w = (uint)f2bf(r6) | ((uint)f2bf(r7) << 16);
        *(uint4*)(out + (size_t)node * 128 + 8 * i) = o;
    }
}

// ---------------- MFMA GEMM2: h2[N][64] bf16 (isd-scaled) = h1 @ W2 ---------
__global__ __launch_bounds__(256) void k_gemm2(const ushort* __restrict__ A,
                                               const float* __restrict__ B,
                                               const int* __restrict__ cnt,
                                               ushort* __restrict__ C, int M) {
    __shared__ __align__(16) ushort As[64][136];   // [m][k] bf16
    __shared__ __align__(16) ushort Bs[64][136];   // [n][k] bf16 (W2^T)
    const int tid  = threadIdx.x;
    const int w    = tid >> 6;
    const int lane = tid & 63;
    const int l15  = lane & 15;
    const int q8   = (lane >> 4) * 8;
    const int row0 = blockIdx.x * 64;

    #pragma unroll
    for (int t = 0; t < 4; ++t) {
        int f = tid * 8 + t * 2048;
        int r = f >> 7;
        int k = f & 127;
        uint4 v = make_uint4(0u, 0u, 0u, 0u);
        int gr = row0 + r;
        if (gr < M) v = *(const uint4*)(A + (size_t)gr * 128 + k);
        *(uint4*)&As[r][k] = v;
    }
    #pragma unroll
    for (int t = 0; t < 8; ++t) {
        int f = tid * 4 + t * 1024;
        int k = f >> 6;
        int n = f & 63;
        float4 v = *(const float4*)(B + (size_t)k * 64 + n);
        Bs[n + 0][k] = f2bf(v.x);
        Bs[n + 1][k] = f2bf(v.y);
        Bs[n + 2][k] = f2bf(v.z);
        Bs[n + 3][k] = f2bf(v.w);
    }
    __syncthreads();

    f32x4 acc[4];
    #pragma unroll
    for (int t = 0; t < 4; ++t) {
        acc[t][0] = 0.f; acc[t][1] = 0.f; acc[t][2] = 0.f; acc[t][3] = 0.f;
    }
    #pragma unroll
    for (int kt = 0; kt < 4; ++kt) {
        short8 a = *(const short8*)&As[16 * w + l15][32 * kt + q8];
        #pragma unroll
        for (int t = 0; t < 4; ++t) {
            short8 b = *(const short8*)&Bs[16 * t + l15][32 * kt + q8];
            acc[t] = __builtin_amdgcn_mfma_f32_16x16x32_bf16(a, b, acc[t], 0, 0, 0);
        }
    }
    const int quad = lane >> 4;
    #pragma unroll
    for (int r = 0; r < 4; ++r) {
        int grow = row0 + 16 * w + quad * 4 + r;
        if (grow < M) {
            float ws = rsqrtf((float)(cnt[grow] + 1));   // pre-scale by isd_src
            #pragma unroll
            for (int t = 0; t < 4; ++t) {
                C[(size_t)grow * 64 + 16 * t + l15] = f2bf(ws * acc[t][r]);
            }
        }
    }
}

// ---------------- agg layer 2: F=64, prescaled bf16 in, fp32 out ------------
__global__ __launch_bounds__(256) void k_agg64(const ushort* __restrict__ h,
                                               const int* __restrict__ cnt,
                                               const ushort* __restrict__ slot,
                                               const float* __restrict__ bias,
                                               const int* __restrict__ ovfcnt,
                                               const int2* __restrict__ ovf,
                                               float* __restrict__ out, int n) {
    int node = (blockIdx.x * 256 + threadIdx.x) >> 6;
    int lane = threadIdx.x & 63;
    if (node >= n) return;
    int deg = cnt[node];
    int degm = min(deg, CAP);
    float isd_i = rsqrtf((float)(deg + 1));
    int sidx = (int)__builtin_nontemporal_load(slot + (size_t)node * CAP + lane);

    const int g = lane >> 3;          // 0..7
    const int i = lane & 7;           // 0..7
    const ushort* hp = h + 8 * i;

    float acc[8] = {};
    for (int j = 0; j < degm; j += 16) {         // 16 edges/iter, 2 gathers
        int j0 = j + g;
        int j1 = j + 8 + g;
        int   s0 = __shfl(sidx, j0);
        int   s1 = __shfl(sidx, j1);
        float w0 = (j0 < degm) ? 1.f : 0.f;
        float w1 = (j1 < degm) ? 1.f : 0.f;
        uint4 v0 = *(const uint4*)(hp + (size_t)s0 * 64);
        uint4 v1 = *(const uint4*)(hp + (size_t)s1 * 64);
        acc[0] += w0 * bf2f_lo(v0.x) + w1 * bf2f_lo(v1.x);
        acc[1] += w0 * bf2f_hi(v0.x) + w1 * bf2f_hi(v1.x);
        acc[2] += w0 * bf2f_lo(v0.y) + w1 * bf2f_lo(v1.y);
        acc[3] += w0 * bf2f_hi(v0.y) + w1 * bf2f_hi(v1.y);
        acc[4] += w0 * bf2f_lo(v0.z) + w1 * bf2f_lo(v1.z);
        acc[5] += w0 * bf2f_hi(v0.z) + w1 * bf2f_hi(v1.z);
        acc[6] += w0 * bf2f_lo(v0.w) + w1 * bf2f_lo(v1.w);
        acc[7] += w0 * bf2f_hi(v0.w) + w1 * bf2f_hi(v1.w);
    }
    int ovn = *ovfcnt;
    for (int t = 0; t < ovn; ++t) {
        int2 p = ovf[t];
        if (p.x == node && g == 0) {             // h2 rows prescaled by isd_s
            uint4 v0 = *(const uint4*)(hp + (size_t)p.y * 64);
            acc[0] += bf2f_lo(v0.x); acc[1] += bf2f_hi(v0.x);
            acc[2] += bf2f_lo(v0.y); acc[3] += bf2f_hi(v0.y);
            acc[4] += bf2f_lo(v0.z); acc[5] += bf2f_hi(v0.z);
            acc[6] += bf2f_lo(v0.w); acc[7] += bf2f_hi(v0.w);
        }
    }
    #pragma unroll
    for (int k = 0; k < 8; ++k) {                // fold octs
        acc[k] += __shfl_xor(acc[k], 8);
        acc[k] += __shfl_xor(acc[k], 16);
        acc[k] += __shfl_xor(acc[k], 32);
    }
    if (g == 0) {
        uint4 vs = *(const uint4*)(hp + (size_t)node * 64);   // scaled self
        float4 ba = *(const float4*)(bias + 8 * i);
        float4 bb = *(const float4*)(bias + 8 * i + 4);
        float4 r0, r1;
        r0.x = (acc[0] + bf2f_lo(vs.x)) * isd_i + ba.x;
        r0.y = (acc[1] + bf2f_hi(vs.x)) * isd_i + ba.y;
        r0.z = (acc[2] + bf2f_lo(vs.y)) * isd_i + ba.z;
        r0.w = (acc[3] + bf2f_hi(vs.y)) * isd_i + ba.w;
        r1.x = (acc[4] + bf2f_lo(vs.z)) * isd_i + bb.x;
        r1.y = (acc[5] + bf2f_hi(vs.z)) * isd_i + bb.y;
        r1.z = (acc[6] + bf2f_lo(vs.w)) * isd_i + bb.z;
        r1.w = (acc[7] + bf2f_hi(vs.w)) * isd_i + bb.w;
        float* op = out + (size_t)node * 64 + 8 * i;
        *(float4*)op = r0;
        *(float4*)(op + 4) = r1;
    }
}

static inline size_t align256(size_t x) { return (x + 255) & ~(size_t)255; }

extern "C" void kernel_launch(void* const* d_in, const int* in_sizes, int n_in,
                              void* d_out, int out_size, void* d_ws, size_t ws_size,
                              hipStream_t stream) {
    const float* x  = (const float*)d_in[0];
    const int*   ei = (const int*)d_in[1];
    const float* W1 = (const float*)d_in[2];
    const float* b1 = (const float*)d_in[3];
    const float* W2 = (const float*)d_in[4];
    const float* b2 = (const float*)d_in[5];
    float* out = (float*)d_out;

    const int N = in_sizes[0] / GCN_IN;   // 50000
    const int E = in_sizes[1] / 2;        // 800000
    const int* src = ei;
    const int* dst = ei + E;

    char* ws = (char*)d_ws;
    size_t o = 0;
    int*    cnt    = (int*)(ws + o);     o += align256((size_t)N * 4);
    int*    ovfcnt = (int*)(ws + o);     o += 256;
    int2*   ovf    = (int2*)(ws + o);    o += align256((size_t)OVF_CAP * 8);
    ushort* slot   = (ushort*)(ws + o);  o += align256((size_t)N * CAP * 2);
    ushort* hb     = (ushort*)(ws + o);  o += align256((size_t)N * GCN_H * 2);
    ushort* h1b    = (ushort*)(ws + o);  o += align256((size_t)N * GCN_H * 2);
    ushort* h2b    = (ushort*)(ws + o);  o += align256((size_t)N * GCN_OUT * 2);

    // zero cnt + ovfcnt (contiguous)
    (void)hipMemsetAsync(cnt, 0, align256((size_t)N * 4) + 256, stream);

    // 1. fused: XCD-partitioned scatter || MFMA GEMM1 -> hb (unscaled bf16)
    {
        int gemm_blocks = (N + 63) / 64;
        k_fused1<<<SCAT_BLOCKS + gemm_blocks, 256, 0, stream>>>(
            src, dst, cnt, slot, ovfcnt, ovf, E, x, W1, hb, N, N);
    }

    // 2. agg layer 1 -> h1b (bf16, per-edge isd weights)
    k_agg128<<<(N * 64 + 255) / 256, 256, 0, stream>>>(hb, cnt, slot, b1,
                                                       ovfcnt, ovf, h1b, N);

    // 3. MFMA GEMM2: h1b @ W2 -> h2b (bf16, isd-scaled epilogue)
    k_gemm2<<<(N + 63) / 64, 256, 0, stream>>>(h1b, W2, cnt, h2b, N);

    // 4. agg layer 2 -> out (fp32)
    k_agg64<<<(N * 64 + 255) / 256, 256, 0, stream>>>(h2b, cnt, slot, b2,
                                                      ovfcnt, ovf, out, N);
}